// Round 2
// baseline (1105.515 us; speedup 1.0000x reference)
//
#include <hip/hip_runtime.h>
#include <hip/hip_bf16.h>
#include <cstdint>

#define N_NODES 20000
#define N_EDGES 320000
#define BATCH 8
#define HID 128
#define BH (BATCH * HID)   // 1024

// ---------------- workspace layout (bytes) ----------------
static constexpr size_t O_DEG  = 0;
static constexpr size_t O_CUR  = 81920;
static constexpr size_t O_OFF  = 163840;
static constexpr size_t O_DINV = 245760;
static constexpr size_t O_CSRS = 327680;
static constexpr size_t O_CSRW = 1609728;
static constexpr size_t O_HBUF = 2891776;   // 160000*128 floats = 81,920,000 B

__global__ void count_deg(const int* __restrict__ col, int* __restrict__ deg) {
    int e = blockIdx.x * 256 + threadIdx.x;
    if (e < N_EDGES) atomicAdd(&deg[col[e]], 1);
}

__global__ void compute_dinv(const int* __restrict__ deg, float* __restrict__ dinv) {
    int i = blockIdx.x * 256 + threadIdx.x;
    if (i < N_NODES) {
        float d = (float)(deg[i] + 1);   // +1 self loop
        dinv[i] = 1.0f / sqrtf(d);
    }
}

__global__ __launch_bounds__(1024) void scan_offsets(const int* __restrict__ deg,
                                                     int* __restrict__ off) {
    __shared__ int part[1024];
    const int CH = 20;  // 1024*20 = 20480 >= 20000
    int tid = threadIdx.x;
    int base = tid * CH;
    int s = 0;
    for (int i = 0; i < CH; ++i) {
        int idx = base + i;
        if (idx < N_NODES) s += deg[idx];
    }
    part[tid] = s;
    __syncthreads();
    for (int d = 1; d < 1024; d <<= 1) {
        int add = 0;
        if (tid >= d) add = part[tid - d];
        __syncthreads();
        part[tid] += add;
        __syncthreads();
    }
    int run = part[tid] - s;   // exclusive prefix of this chunk
    for (int i = 0; i < CH; ++i) {
        int idx = base + i;
        if (idx < N_NODES) {
            off[idx] = run;
            run += deg[idx];
        }
    }
    if (tid == 1023) off[N_NODES] = part[1023];
}

__global__ void fill_csr(const int* __restrict__ rowi, const int* __restrict__ coli,
                         const float* __restrict__ dinv, const int* __restrict__ off,
                         int* __restrict__ cursor, int* __restrict__ csr_src,
                         float* __restrict__ csr_w) {
    int e = blockIdx.x * 256 + threadIdx.x;
    if (e >= N_EDGES) return;
    int r = rowi[e], c = coli[e];
    int pos = atomicAdd(&cursor[c], 1);
    int i = off[c] + pos;
    csr_src[i] = r;
    csr_w[i] = dinv[r] * dinv[c];
}

// h0[n][b][h] = concat(x[b,n,:6], fixed[n,:10]) @ W_in + b_in
__global__ __launch_bounds__(256) void input_proj(const float* __restrict__ x,
                                                  const float* __restrict__ fixedf,
                                                  const float* __restrict__ W,
                                                  const float* __restrict__ bvec,
                                                  float* __restrict__ h) {
    __shared__ float Ws[16 * HID];
    __shared__ float xs[BATCH * 6];
    __shared__ float fs[10];
    int n = blockIdx.x, tid = threadIdx.x;
    for (int i = tid; i < 16 * HID; i += 256) Ws[i] = W[i];
    if (tid < 48) {
        int b_ = tid / 6, o = tid % 6;
        xs[tid] = x[((size_t)b_ * N_NODES + n) * 6 + o];
    } else if (tid < 58) {
        fs[tid - 48] = fixedf[(size_t)n * 10 + (tid - 48)];
    }
    __syncthreads();
#pragma unroll
    for (int j = 0; j < 4; ++j) {
        int idx = tid + j * 256;     // 0..1023
        int bb = idx >> 7, hh = idx & 127;
        float acc = bvec[hh];
#pragma unroll
        for (int k = 0; k < 6; ++k) acc += xs[bb * 6 + k] * Ws[k * HID + hh];
#pragma unroll
        for (int k = 0; k < 10; ++k) acc += fs[k] * Ws[(6 + k) * HID + hh];
        h[(size_t)n * BH + idx] = acc;
    }
}

// Fused per-layer: agg = dinv^2*h[n] + sum_e w*h[src];  out = relu(agg @ W + b)
// One block per node. agg tile [8][128] lives in registers then LDS.
__global__ __launch_bounds__(256) void gcn_layer(const float* __restrict__ hin,
                                                 const int* __restrict__ off,
                                                 const int* __restrict__ csr_src,
                                                 const float* __restrict__ csr_w,
                                                 const float* __restrict__ dinv,
                                                 const float* __restrict__ W,
                                                 const float* __restrict__ bias,
                                                 float* __restrict__ hout,
                                                 int final_layout) {
    __shared__ float agg_s[BH];   // 4 KB
    int n = blockIdx.x, tid = threadIdx.x;
    float d = dinv[n];
    float d2 = d * d;
    float4 acc = ((const float4*)(hin + (size_t)n * BH))[tid];
    acc.x *= d2; acc.y *= d2; acc.z *= d2; acc.w *= d2;

    int s = off[n], e = off[n + 1];
    int p = s;
    // unroll-4: 4 independent index loads then 4 independent gathers in flight
    for (; p + 4 <= e; p += 4) {
        int s0 = csr_src[p], s1 = csr_src[p + 1], s2 = csr_src[p + 2], s3 = csr_src[p + 3];
        float w0 = csr_w[p], w1 = csr_w[p + 1], w2 = csr_w[p + 2], w3 = csr_w[p + 3];
        float4 v0 = ((const float4*)(hin + (size_t)s0 * BH))[tid];
        float4 v1 = ((const float4*)(hin + (size_t)s1 * BH))[tid];
        float4 v2 = ((const float4*)(hin + (size_t)s2 * BH))[tid];
        float4 v3 = ((const float4*)(hin + (size_t)s3 * BH))[tid];
        acc.x += w0 * v0.x + w1 * v1.x + w2 * v2.x + w3 * v3.x;
        acc.y += w0 * v0.y + w1 * v1.y + w2 * v2.y + w3 * v3.y;
        acc.z += w0 * v0.z + w1 * v1.z + w2 * v2.z + w3 * v3.z;
        acc.w += w0 * v0.w + w1 * v1.w + w2 * v2.w + w3 * v3.w;
    }
    for (; p < e; ++p) {
        int src = csr_src[p];
        float w = csr_w[p];
        float4 v = ((const float4*)(hin + (size_t)src * BH))[tid];
        acc.x += w * v.x; acc.y += w * v.y; acc.z += w * v.z; acc.w += w * v.w;
    }
    ((float4*)agg_s)[tid] = acc;
    __syncthreads();

    // GEMM phase: thread -> (b = tid>>5, cols j0..j0+3)
    int b = tid >> 5;
    int j0 = (tid & 31) << 2;
    float4 o = *(const float4*)&bias[j0];
    const float* arow = agg_s + b * HID;
#pragma unroll 8
    for (int k = 0; k < HID; ++k) {
        float a = arow[k];
        float4 w4 = *(const float4*)&W[(size_t)k * HID + j0];
        o.x += a * w4.x; o.y += a * w4.y; o.z += a * w4.z; o.w += a * w4.w;
    }
    o.x = fmaxf(o.x, 0.0f); o.y = fmaxf(o.y, 0.0f);
    o.z = fmaxf(o.z, 0.0f); o.w = fmaxf(o.w, 0.0f);
    size_t base = final_layout ? ((size_t)b * N_NODES + n) * HID + j0
                               : (size_t)n * BH + b * HID + j0;
    *(float4*)&hout[base] = o;
}

extern "C" void kernel_launch(void* const* d_in, const int* in_sizes, int n_in,
                              void* d_out, int out_size, void* d_ws, size_t ws_size,
                              hipStream_t stream) {
    const float* x      = (const float*)d_in[0];
    const float* fixedf = (const float*)d_in[1];
    const float* W_in   = (const float*)d_in[2];
    const float* b_in   = (const float*)d_in[3];
    const float* Wg     = (const float*)d_in[4];
    const float* bg     = (const float*)d_in[5];
    const int*   ei     = (const int*)d_in[6];

    const int* rowi = ei;
    const int* coli = ei + N_EDGES;

    char* ws = (char*)d_ws;
    int*   deg     = (int*)(ws + O_DEG);
    int*   cursor  = (int*)(ws + O_CUR);
    int*   off     = (int*)(ws + O_OFF);
    float* dinv    = (float*)(ws + O_DINV);
    int*   csr_src = (int*)(ws + O_CSRS);
    float* csr_w   = (float*)(ws + O_CSRW);
    float* hbufA   = (float*)(ws + O_HBUF);   // 82 MB node-feature buffer
    float* hbufB   = (float*)d_out;           // d_out doubles as intermediate

    hipMemsetAsync(deg, 0, N_NODES * sizeof(int), stream);
    hipMemsetAsync(cursor, 0, N_NODES * sizeof(int), stream);

    count_deg<<<(N_EDGES + 255) / 256, 256, 0, stream>>>(coli, deg);
    compute_dinv<<<(N_NODES + 255) / 256, 256, 0, stream>>>(deg, dinv);
    scan_offsets<<<1, 1024, 0, stream>>>(deg, off);
    fill_csr<<<(N_EDGES + 255) / 256, 256, 0, stream>>>(rowi, coli, dinv, off, cursor,
                                                        csr_src, csr_w);

    input_proj<<<N_NODES, 256, 0, stream>>>(x, fixedf, W_in, b_in, hbufA);

    // L0: A -> B(d_out), L1: B -> A, L2: A -> d_out (final [b][n][h] layout)
    gcn_layer<<<N_NODES, 256, 0, stream>>>(hbufA, off, csr_src, csr_w, dinv,
                                           Wg + 0 * HID * HID, bg + 0 * HID, hbufB, 0);
    gcn_layer<<<N_NODES, 256, 0, stream>>>(hbufB, off, csr_src, csr_w, dinv,
                                           Wg + 1 * HID * HID, bg + 1 * HID, hbufA, 0);
    gcn_layer<<<N_NODES, 256, 0, stream>>>(hbufA, off, csr_src, csr_w, dinv,
                                           Wg + 2 * HID * HID, bg + 2 * HID, (float*)d_out, 1);
}

// Round 3
// 912.781 us; speedup vs baseline: 1.2112x; 1.2112x over previous
//
#include <hip/hip_runtime.h>
#include <hip/hip_bf16.h>
#include <cstdint>

#define N_NODES 20000
#define N_EDGES 320000
#define BATCH 8
#define HID 128
#define BH (BATCH * HID)   // 1024

// ---------------- workspace layout (bytes) ----------------
// deg:    20000 int     @ 0
// cursor: 20000 int     @ 81920
// off:    20001 int     @ 163840
// dinv:   20000 float   @ 245760
// csr:    320000 int2   @ 327680   (src, w-bits packed; 2,560,000 B)
// hA:     160000*128 f  @ 2891776  (81,920,000 B)  -> total ~84.8 MB
static constexpr size_t O_DEG  = 0;
static constexpr size_t O_CUR  = 81920;
static constexpr size_t O_OFF  = 163840;
static constexpr size_t O_DINV = 245760;
static constexpr size_t O_CSR  = 327680;
static constexpr size_t O_HBUF = 2891776;

__global__ void count_deg(const int* __restrict__ col, int* __restrict__ deg) {
    int e = blockIdx.x * 256 + threadIdx.x;
    if (e < N_EDGES) atomicAdd(&deg[col[e]], 1);
}

__global__ void compute_dinv(const int* __restrict__ deg, float* __restrict__ dinv) {
    int i = blockIdx.x * 256 + threadIdx.x;
    if (i < N_NODES) {
        float d = (float)(deg[i] + 1);   // +1 self loop
        dinv[i] = 1.0f / sqrtf(d);
    }
}

__global__ __launch_bounds__(1024) void scan_offsets(const int* __restrict__ deg,
                                                     int* __restrict__ off) {
    __shared__ int part[1024];
    const int CH = 20;  // 1024*20 = 20480 >= 20000
    int tid = threadIdx.x;
    int base = tid * CH;
    int s = 0;
    for (int i = 0; i < CH; ++i) {
        int idx = base + i;
        if (idx < N_NODES) s += deg[idx];
    }
    part[tid] = s;
    __syncthreads();
    for (int d = 1; d < 1024; d <<= 1) {
        int add = 0;
        if (tid >= d) add = part[tid - d];
        __syncthreads();
        part[tid] += add;
        __syncthreads();
    }
    int run = part[tid] - s;   // exclusive prefix of this chunk
    for (int i = 0; i < CH; ++i) {
        int idx = base + i;
        if (idx < N_NODES) {
            off[idx] = run;
            run += deg[idx];
        }
    }
    if (tid == 1023) off[N_NODES] = part[1023];
}

__global__ void fill_csr(const int* __restrict__ rowi, const int* __restrict__ coli,
                         const float* __restrict__ dinv, const int* __restrict__ off,
                         int* __restrict__ cursor, int2* __restrict__ csr) {
    int e = blockIdx.x * 256 + threadIdx.x;
    if (e >= N_EDGES) return;
    int r = rowi[e], c = coli[e];
    int pos = atomicAdd(&cursor[c], 1);
    int i = off[c] + pos;
    csr[i] = make_int2(r, __float_as_int(dinv[r] * dinv[c]));
}

// h0[n][b][h] = concat(x[b,n,:6], fixed[n,:10]) @ W_in + b_in
__global__ __launch_bounds__(256) void input_proj(const float* __restrict__ x,
                                                  const float* __restrict__ fixedf,
                                                  const float* __restrict__ W,
                                                  const float* __restrict__ bvec,
                                                  float* __restrict__ h) {
    __shared__ float Ws[16 * HID];
    __shared__ float xs[BATCH * 6];
    __shared__ float fs[10];
    int n = blockIdx.x, tid = threadIdx.x;
    for (int i = tid; i < 16 * HID; i += 256) Ws[i] = W[i];
    if (tid < 48) {
        int b_ = tid / 6, o = tid % 6;
        xs[tid] = x[((size_t)b_ * N_NODES + n) * 6 + o];
    } else if (tid < 58) {
        fs[tid - 48] = fixedf[(size_t)n * 10 + (tid - 48)];
    }
    __syncthreads();
#pragma unroll
    for (int j = 0; j < 4; ++j) {
        int idx = tid + j * 256;     // 0..1023
        int bb = idx >> 7, hh = idx & 127;
        float acc = bvec[hh];
#pragma unroll
        for (int k = 0; k < 6; ++k) acc += xs[bb * 6 + k] * Ws[k * HID + hh];
#pragma unroll
        for (int k = 0; k < 10; ++k) acc += fs[k] * Ws[(6 + k) * HID + hh];
        h[(size_t)n * BH + idx] = acc;
    }
}

// agg[n][:] = dinv[n]^2 * h[n][:] + sum_{in-edges} w * h[src][:]
// unroll-8 with masked tail: 8 independent (index,gather) pairs in flight.
// final_scatter: write batch-major rows (out row b*N+n) for the last layer.
__global__ __launch_bounds__(256) void aggregate(const float* __restrict__ hin,
                                                 const int* __restrict__ off,
                                                 const int2* __restrict__ csr,
                                                 const float* __restrict__ dinv,
                                                 float* __restrict__ out,
                                                 int final_scatter) {
    int n = blockIdx.x, tid = threadIdx.x;
    float d = dinv[n];
    float d2 = d * d;
    const float4* hp4 = (const float4*)hin;
    float4 acc = hp4[(size_t)n * 256 + tid];
    acc.x *= d2; acc.y *= d2; acc.z *= d2; acc.w *= d2;

    int s = off[n], e = off[n + 1];
    for (int p = s; p < e; p += 8) {
        int   si[8];
        float wv[8];
#pragma unroll
        for (int u = 0; u < 8; ++u) {
            int q = (p + u < e) ? (p + u) : (e - 1);
            int2 sw = csr[q];
            si[u] = sw.x;
            wv[u] = (p + u < e) ? __int_as_float(sw.y) : 0.0f;
        }
        float4 v[8];
#pragma unroll
        for (int u = 0; u < 8; ++u) v[u] = hp4[(size_t)si[u] * 256 + tid];
#pragma unroll
        for (int u = 0; u < 8; ++u) {
            acc.x += wv[u] * v[u].x;
            acc.y += wv[u] * v[u].y;
            acc.z += wv[u] * v[u].z;
            acc.w += wv[u] * v[u].w;
        }
    }

    if (final_scatter) {
        int b = tid >> 5;                 // batch
        int h0 = (tid & 31) << 2;         // feature offset
        *(float4*)&out[((size_t)b * N_NODES + n) * HID + h0] = acc;
    } else {
        ((float4*)(out + (size_t)n * BH))[tid] = acc;
    }
}

// In-place row transform: data[r,:] = relu(data[r,:] @ W + bias)
// Safe in-place: each row is read fully (k-tiles into LDS) before any write,
// and rows are owned by exactly one block.
__global__ __launch_bounds__(256) void gemm_bias_relu(float* data,
                                                      const float* __restrict__ W,
                                                      const float* __restrict__ bias) {
    __shared__ float As[128][32];
    __shared__ float Wls[32][HID];
    int tid = threadIdx.x;
    int tx = tid & 31;   // cols tx*4..tx*4+3
    int ty = tid >> 5;   // rows ty*16..ty*16+15
    size_t m0 = (size_t)blockIdx.x * 128;
    float acc[16][4] = {};
    for (int kt = 0; kt < HID; kt += 32) {
        __syncthreads();
#pragma unroll
        for (int i = 0; i < 4; ++i) {
            int f = tid + i * 256;          // float4 index over 128x32 = 1024
            int row = f >> 3;
            int kk = (f & 7) << 2;
            *(float4*)&As[row][kk] = *(const float4*)&data[(m0 + row) * HID + kt + kk];
        }
#pragma unroll
        for (int i = 0; i < 4; ++i) {
            int f = tid + i * 256;          // float4 index over 32x128 = 1024
            int row = f >> 5;
            int kk = (f & 31) << 2;
            *(float4*)&Wls[row][kk] = *(const float4*)&W[(size_t)(kt + row) * HID + kk];
        }
        __syncthreads();
#pragma unroll
        for (int k = 0; k < 32; ++k) {
            float4 w4 = *(const float4*)&Wls[k][tx << 2];
#pragma unroll
            for (int rr = 0; rr < 16; ++rr) {
                float a = As[ty * 16 + rr][k];
                acc[rr][0] += a * w4.x;
                acc[rr][1] += a * w4.y;
                acc[rr][2] += a * w4.z;
                acc[rr][3] += a * w4.w;
            }
        }
    }
    float4 b4 = *(const float4*)&bias[tx << 2];
#pragma unroll
    for (int rr = 0; rr < 16; ++rr) {
        size_t r = m0 + ty * 16 + rr;
        float4 o;
        o.x = fmaxf(acc[rr][0] + b4.x, 0.0f);
        o.y = fmaxf(acc[rr][1] + b4.y, 0.0f);
        o.z = fmaxf(acc[rr][2] + b4.z, 0.0f);
        o.w = fmaxf(acc[rr][3] + b4.w, 0.0f);
        *(float4*)&data[r * HID + (tx << 2)] = o;
    }
}

extern "C" void kernel_launch(void* const* d_in, const int* in_sizes, int n_in,
                              void* d_out, int out_size, void* d_ws, size_t ws_size,
                              hipStream_t stream) {
    const float* x      = (const float*)d_in[0];
    const float* fixedf = (const float*)d_in[1];
    const float* W_in   = (const float*)d_in[2];
    const float* b_in   = (const float*)d_in[3];
    const float* Wg     = (const float*)d_in[4];
    const float* bg     = (const float*)d_in[5];
    const int*   ei     = (const int*)d_in[6];

    const int* rowi = ei;
    const int* coli = ei + N_EDGES;

    char* ws = (char*)d_ws;
    int*   deg     = (int*)(ws + O_DEG);
    int*   cursor  = (int*)(ws + O_CUR);
    int*   off     = (int*)(ws + O_OFF);
    float* dinv    = (float*)(ws + O_DINV);
    int2*  csr     = (int2*)(ws + O_CSR);
    float* hA      = (float*)(ws + O_HBUF);   // 82 MB node-feature buffer
    float* hB      = (float*)d_out;           // d_out doubles as intermediate

    hipMemsetAsync(deg, 0, N_NODES * sizeof(int), stream);
    hipMemsetAsync(cursor, 0, N_NODES * sizeof(int), stream);

    count_deg<<<(N_EDGES + 255) / 256, 256, 0, stream>>>(coli, deg);
    compute_dinv<<<(N_NODES + 255) / 256, 256, 0, stream>>>(deg, dinv);
    scan_offsets<<<1, 1024, 0, stream>>>(deg, off);
    fill_csr<<<(N_EDGES + 255) / 256, 256, 0, stream>>>(rowi, coli, dinv, off, cursor, csr);

    input_proj<<<N_NODES, 256, 0, stream>>>(x, fixedf, W_in, b_in, hA);

    const int GB = (BATCH * N_NODES) / 128;   // 1250 gemm blocks

    // L0: hA --agg--> hB(d_out) --gemm in-place--> h1 in hB
    aggregate<<<N_NODES, 256, 0, stream>>>(hA, off, csr, dinv, hB, 0);
    gemm_bias_relu<<<GB, 256, 0, stream>>>(hB, Wg + 0 * HID * HID, bg + 0 * HID);
    // L1: hB --agg--> hA --gemm in-place--> h2 in hA
    aggregate<<<N_NODES, 256, 0, stream>>>(hB, off, csr, dinv, hA, 0);
    gemm_bias_relu<<<GB, 256, 0, stream>>>(hA, Wg + 1 * HID * HID, bg + 1 * HID);
    // L2: hA --agg(scatter to [b][n])--> d_out --gemm in-place--> final
    aggregate<<<N_NODES, 256, 0, stream>>>(hA, off, csr, dinv, (float*)d_out, 1);
    gemm_bias_relu<<<GB, 256, 0, stream>>>((float*)d_out, Wg + 2 * HID * HID, bg + 2 * HID);
}

// Round 4
// 830.096 us; speedup vs baseline: 1.3318x; 1.0996x over previous
//
#include <hip/hip_runtime.h>
#include <hip/hip_bf16.h>
#include <cstdint>

#define N_NODES 20000
#define N_EDGES 320000
#define BATCH 8
#define HID 128
#define BH (BATCH * HID)   // 1024

// ---------------- workspace layout (bytes) ----------------
static constexpr size_t O_DEG  = 0;
static constexpr size_t O_CUR  = 81920;
static constexpr size_t O_OFF  = 163840;
static constexpr size_t O_DINV = 245760;
static constexpr size_t O_CSR  = 327680;    // 320000 int2 = 2,560,000 B
static constexpr size_t O_HBUF = 2891776;   // 160000*128 f = 81,920,000 B

__global__ void count_deg(const int* __restrict__ col, int* __restrict__ deg) {
    int e = blockIdx.x * 256 + threadIdx.x;
    if (e < N_EDGES) atomicAdd(&deg[col[e]], 1);
}

__global__ void compute_dinv(const int* __restrict__ deg, float* __restrict__ dinv) {
    int i = blockIdx.x * 256 + threadIdx.x;
    if (i < N_NODES) {
        float d = (float)(deg[i] + 1);   // +1 self loop
        dinv[i] = 1.0f / sqrtf(d);
    }
}

__global__ __launch_bounds__(1024) void scan_offsets(const int* __restrict__ deg,
                                                     int* __restrict__ off) {
    __shared__ int part[1024];
    const int CH = 20;
    int tid = threadIdx.x;
    int base = tid * CH;
    int s = 0;
    for (int i = 0; i < CH; ++i) {
        int idx = base + i;
        if (idx < N_NODES) s += deg[idx];
    }
    part[tid] = s;
    __syncthreads();
    for (int d = 1; d < 1024; d <<= 1) {
        int add = 0;
        if (tid >= d) add = part[tid - d];
        __syncthreads();
        part[tid] += add;
        __syncthreads();
    }
    int run = part[tid] - s;
    for (int i = 0; i < CH; ++i) {
        int idx = base + i;
        if (idx < N_NODES) {
            off[idx] = run;
            run += deg[idx];
        }
    }
    if (tid == 1023) off[N_NODES] = part[1023];
}

__global__ void fill_csr(const int* __restrict__ rowi, const int* __restrict__ coli,
                         const float* __restrict__ dinv, const int* __restrict__ off,
                         int* __restrict__ cursor, int2* __restrict__ csr) {
    int e = blockIdx.x * 256 + threadIdx.x;
    if (e >= N_EDGES) return;
    int r = rowi[e], c = coli[e];
    int pos = atomicAdd(&cursor[c], 1);
    int i = off[c] + pos;
    csr[i] = make_int2(r, __float_as_int(dinv[r] * dinv[c]));
}

// h0[n][b][h] = concat(x[b,n,:6], fixed[n,:10]) @ W_in + b_in
__global__ __launch_bounds__(256) void input_proj(const float* __restrict__ x,
                                                  const float* __restrict__ fixedf,
                                                  const float* __restrict__ W,
                                                  const float* __restrict__ bvec,
                                                  float* __restrict__ h) {
    __shared__ float Ws[16 * HID];
    __shared__ float xs[BATCH * 6];
    __shared__ float fs[10];
    int n = blockIdx.x, tid = threadIdx.x;
    for (int i = tid; i < 16 * HID; i += 256) Ws[i] = W[i];
    if (tid < 48) {
        int b_ = tid / 6, o = tid % 6;
        xs[tid] = x[((size_t)b_ * N_NODES + n) * 6 + o];
    } else if (tid < 58) {
        fs[tid - 48] = fixedf[(size_t)n * 10 + (tid - 48)];
    }
    __syncthreads();
#pragma unroll
    for (int j = 0; j < 4; ++j) {
        int idx = tid + j * 256;
        int bb = idx >> 7, hh = idx & 127;
        float acc = bvec[hh];
#pragma unroll
        for (int k = 0; k < 6; ++k) acc += xs[bb * 6 + k] * Ws[k * HID + hh];
#pragma unroll
        for (int k = 0; k < 10; ++k) acc += fs[k] * Ws[(6 + k) * HID + hh];
        h[(size_t)n * BH + idx] = acc;
    }
}

// Batch-split aggregation: grid = (N/4, 4). blockIdx.y = batch-pair pass.
// One wave per node per pass; each lane owns one float4 of the 1KB chunk.
// Passes are temporally ordered (x dispatches fastest) so the gather working
// set per pass is ~20.5 MB instead of 82 MB -> better L2 hit rate.
__global__ __launch_bounds__(256) void aggregate_bp(const float* __restrict__ hin,
                                                    const int* __restrict__ off,
                                                    const int2* __restrict__ csr,
                                                    const float* __restrict__ dinv,
                                                    float* __restrict__ out,
                                                    int final_scatter) {
    int w = threadIdx.x >> 6;
    int lane = threadIdx.x & 63;
    int n = blockIdx.x * 4 + w;
    int bp = blockIdx.y;             // batch pair 0..3
    const float4* hp4 = (const float4*)hin;
    int chunk = bp * 64 + lane;      // float4 index within a node's 256-float4 row

    float d = dinv[n];
    float d2 = d * d;
    float4 acc = hp4[(size_t)n * 256 + chunk];
    acc.x *= d2; acc.y *= d2; acc.z *= d2; acc.w *= d2;

    int s = off[n], e = off[n + 1];
    for (int p = s; p < e; p += 4) {
        int   si[4];
        float wv[4];
#pragma unroll
        for (int u = 0; u < 4; ++u) {
            int q = (p + u < e) ? (p + u) : (e - 1);
            int2 sw = csr[q];
            si[u] = sw.x;
            wv[u] = (p + u < e) ? __int_as_float(sw.y) : 0.0f;
        }
        float4 v[4];
#pragma unroll
        for (int u = 0; u < 4; ++u) v[u] = hp4[(size_t)si[u] * 256 + chunk];
#pragma unroll
        for (int u = 0; u < 4; ++u) {
            acc.x += wv[u] * v[u].x;
            acc.y += wv[u] * v[u].y;
            acc.z += wv[u] * v[u].z;
            acc.w += wv[u] * v[u].w;
        }
    }

    if (final_scatter) {
        int b = bp * 2 + (lane >> 5);
        int col = (lane & 31) << 2;
        *(float4*)&out[((size_t)b * N_NODES + n) * HID + col] = acc;
    } else {
        ((float4*)out)[(size_t)n * 256 + chunk] = acc;
    }
}

// In-place row transform: data[r,:] = relu(data[r,:] @ W + bias)
// 128-row tiles, transposed A in LDS, 8x8 register tile per thread.
__global__ __launch_bounds__(256) void gemm_bias_relu(float* data,
                                                      const float* __restrict__ W,
                                                      const float* __restrict__ bias) {
    __shared__ float As_T[32][136];   // [k][row], stride 136 floats (16B-aligned rows)
    __shared__ float Wls[32][HID];    // [k][col]
    int tid = threadIdx.x;
    int rg = tid >> 4;    // row group: rows rg*8 .. rg*8+7
    int cg = tid & 15;    // col group: cols cg*8 .. cg*8+7
    size_t m0 = (size_t)blockIdx.x * 128;
    float acc[8][8] = {};

    for (int kt = 0; kt < HID; kt += 32) {
        __syncthreads();
#pragma unroll
        for (int i = 0; i < 4; ++i) {
            int f = tid + i * 256;          // 0..1023 over 128 rows x 8 float4s
            int row = f >> 3;
            int kk = (f & 7) << 2;
            float4 v = *(const float4*)&data[(m0 + row) * HID + kt + kk];
            As_T[kk + 0][row] = v.x;
            As_T[kk + 1][row] = v.y;
            As_T[kk + 2][row] = v.z;
            As_T[kk + 3][row] = v.w;
        }
#pragma unroll
        for (int i = 0; i < 4; ++i) {
            int f = tid + i * 256;          // 0..1023 over 32 rows x 32 float4s
            int row = f >> 5;
            int kk = (f & 31) << 2;
            *(float4*)&Wls[row][kk] = *(const float4*)&W[(size_t)(kt + row) * HID + kk];
        }
        __syncthreads();
#pragma unroll 8
        for (int k = 0; k < 32; ++k) {
            float4 a0 = *(const float4*)&As_T[k][rg * 8];
            float4 a1 = *(const float4*)&As_T[k][rg * 8 + 4];
            float4 w0 = *(const float4*)&Wls[k][cg * 8];
            float4 w1 = *(const float4*)&Wls[k][cg * 8 + 4];
            float av[8] = {a0.x, a0.y, a0.z, a0.w, a1.x, a1.y, a1.z, a1.w};
            float wv[8] = {w0.x, w0.y, w0.z, w0.w, w1.x, w1.y, w1.z, w1.w};
#pragma unroll
            for (int i = 0; i < 8; ++i)
#pragma unroll
                for (int j = 0; j < 8; ++j)
                    acc[i][j] += av[i] * wv[j];
        }
    }

    float4 b0 = *(const float4*)&bias[cg * 8];
    float4 b1 = *(const float4*)&bias[cg * 8 + 4];
#pragma unroll
    for (int i = 0; i < 8; ++i) {
        size_t r = m0 + rg * 8 + i;
        float4 o0, o1;
        o0.x = fmaxf(acc[i][0] + b0.x, 0.0f);
        o0.y = fmaxf(acc[i][1] + b0.y, 0.0f);
        o0.z = fmaxf(acc[i][2] + b0.z, 0.0f);
        o0.w = fmaxf(acc[i][3] + b0.w, 0.0f);
        o1.x = fmaxf(acc[i][4] + b1.x, 0.0f);
        o1.y = fmaxf(acc[i][5] + b1.y, 0.0f);
        o1.z = fmaxf(acc[i][6] + b1.z, 0.0f);
        o1.w = fmaxf(acc[i][7] + b1.w, 0.0f);
        *(float4*)&data[r * HID + cg * 8] = o0;
        *(float4*)&data[r * HID + cg * 8 + 4] = o1;
    }
}

extern "C" void kernel_launch(void* const* d_in, const int* in_sizes, int n_in,
                              void* d_out, int out_size, void* d_ws, size_t ws_size,
                              hipStream_t stream) {
    const float* x      = (const float*)d_in[0];
    const float* fixedf = (const float*)d_in[1];
    const float* W_in   = (const float*)d_in[2];
    const float* b_in   = (const float*)d_in[3];
    const float* Wg     = (const float*)d_in[4];
    const float* bg     = (const float*)d_in[5];
    const int*   ei     = (const int*)d_in[6];

    const int* rowi = ei;
    const int* coli = ei + N_EDGES;

    char* ws = (char*)d_ws;
    int*   deg     = (int*)(ws + O_DEG);
    int*   cursor  = (int*)(ws + O_CUR);
    int*   off     = (int*)(ws + O_OFF);
    float* dinv    = (float*)(ws + O_DINV);
    int2*  csr     = (int2*)(ws + O_CSR);
    float* hA      = (float*)(ws + O_HBUF);
    float* hB      = (float*)d_out;

    hipMemsetAsync(deg, 0, N_NODES * sizeof(int), stream);
    hipMemsetAsync(cursor, 0, N_NODES * sizeof(int), stream);

    count_deg<<<(N_EDGES + 255) / 256, 256, 0, stream>>>(coli, deg);
    compute_dinv<<<(N_NODES + 255) / 256, 256, 0, stream>>>(deg, dinv);
    scan_offsets<<<1, 1024, 0, stream>>>(deg, off);
    fill_csr<<<(N_EDGES + 255) / 256, 256, 0, stream>>>(rowi, coli, dinv, off, cursor, csr);

    input_proj<<<N_NODES, 256, 0, stream>>>(x, fixedf, W_in, b_in, hA);

    const dim3 AG(N_NODES / 4, 4);
    const int GB = (BATCH * N_NODES) / 128;   // 1250 gemm blocks

    // L0: hA --agg--> hB(d_out) --gemm in-place--> h1 in hB
    aggregate_bp<<<AG, 256, 0, stream>>>(hA, off, csr, dinv, hB, 0);
    gemm_bias_relu<<<GB, 256, 0, stream>>>(hB, Wg + 0 * HID * HID, bg + 0 * HID);
    // L1: hB --agg--> hA --gemm in-place--> h2 in hA
    aggregate_bp<<<AG, 256, 0, stream>>>(hB, off, csr, dinv, hA, 0);
    gemm_bias_relu<<<GB, 256, 0, stream>>>(hA, Wg + 1 * HID * HID, bg + 1 * HID);
    // L2: hA --agg(scatter [b][n])--> d_out --gemm in-place--> final
    aggregate_bp<<<AG, 256, 0, stream>>>(hA, off, csr, dinv, (float*)d_out, 1);
    gemm_bias_relu<<<GB, 256, 0, stream>>>((float*)d_out, Wg + 2 * HID * HID, bg + 2 * HID);
}

// Round 5
// 796.030 us; speedup vs baseline: 1.3888x; 1.0428x over previous
//
#include <hip/hip_runtime.h>
#include <hip/hip_bf16.h>
#include <cstdint>

#define N_NODES 20000
#define N_EDGES 320000
#define BATCH 8
#define HID 128
#define BH (BATCH * HID)   // 1024
#define WPB 16             // waves (=nodes) per fused-layer block

// ---------------- workspace layout (bytes) ----------------
static constexpr size_t O_DEG  = 0;
static constexpr size_t O_CUR  = 81920;
static constexpr size_t O_OFF  = 163840;
static constexpr size_t O_DINV = 245760;
static constexpr size_t O_CSR  = 327680;    // 320000 int2 = 2,560,000 B
static constexpr size_t O_HBUF = 2891776;   // 160000*128 f = 81,920,000 B

__global__ void count_deg(const int* __restrict__ col, int* __restrict__ deg) {
    int e = blockIdx.x * 256 + threadIdx.x;
    if (e < N_EDGES) atomicAdd(&deg[col[e]], 1);
}

__global__ void compute_dinv(const int* __restrict__ deg, float* __restrict__ dinv) {
    int i = blockIdx.x * 256 + threadIdx.x;
    if (i < N_NODES) {
        float d = (float)(deg[i] + 1);   // +1 self loop
        dinv[i] = 1.0f / sqrtf(d);
    }
}

__global__ __launch_bounds__(1024) void scan_offsets(const int* __restrict__ deg,
                                                     int* __restrict__ off) {
    __shared__ int part[1024];
    const int CH = 20;
    int tid = threadIdx.x;
    int base = tid * CH;
    int s = 0;
    for (int i = 0; i < CH; ++i) {
        int idx = base + i;
        if (idx < N_NODES) s += deg[idx];
    }
    part[tid] = s;
    __syncthreads();
    for (int d = 1; d < 1024; d <<= 1) {
        int add = 0;
        if (tid >= d) add = part[tid - d];
        __syncthreads();
        part[tid] += add;
        __syncthreads();
    }
    int run = part[tid] - s;
    for (int i = 0; i < CH; ++i) {
        int idx = base + i;
        if (idx < N_NODES) {
            off[idx] = run;
            run += deg[idx];
        }
    }
    if (tid == 1023) off[N_NODES] = part[1023];
}

__global__ void fill_csr(const int* __restrict__ rowi, const int* __restrict__ coli,
                         const float* __restrict__ dinv, const int* __restrict__ off,
                         int* __restrict__ cursor, int2* __restrict__ csr) {
    int e = blockIdx.x * 256 + threadIdx.x;
    if (e >= N_EDGES) return;
    int r = rowi[e], c = coli[e];
    int pos = atomicAdd(&cursor[c], 1);
    int i = off[c] + pos;
    csr[i] = make_int2(r, __float_as_int(dinv[r] * dinv[c]));
}

// h0[n][b][h] = concat(x[b,n,:6], fixed[n,:10]) @ W_in + b_in
__global__ __launch_bounds__(256) void input_proj(const float* __restrict__ x,
                                                  const float* __restrict__ fixedf,
                                                  const float* __restrict__ W,
                                                  const float* __restrict__ bvec,
                                                  float* __restrict__ h) {
    __shared__ float Ws[16 * HID];
    __shared__ float xs[BATCH * 6];
    __shared__ float fs[10];
    int n = blockIdx.x, tid = threadIdx.x;
    for (int i = tid; i < 16 * HID; i += 256) Ws[i] = W[i];
    if (tid < 48) {
        int b_ = tid / 6, o = tid % 6;
        xs[tid] = x[((size_t)b_ * N_NODES + n) * 6 + o];
    } else if (tid < 58) {
        fs[tid - 48] = fixedf[(size_t)n * 10 + (tid - 48)];
    }
    __syncthreads();
#pragma unroll
    for (int j = 0; j < 4; ++j) {
        int idx = tid + j * 256;
        int bb = idx >> 7, hh = idx & 127;
        float acc = bvec[hh];
#pragma unroll
        for (int k = 0; k < 6; ++k) acc += xs[bb * 6 + k] * Ws[k * HID + hh];
#pragma unroll
        for (int k = 0; k < 10; ++k) acc += fs[k] * Ws[(6 + k) * HID + hh];
        h[(size_t)n * BH + idx] = acc;
    }
}

// Fused GCN layer, wave-per-node:
//  - block stages W (64KB) into LDS once (single __syncthreads)
//  - each wave independently: gather node row [8][128] into regs,
//    spill to private padded LDS tile (wave-local lgkmcnt sync),
//    GEMM+bias+relu from LDS, store.
// LDS = 65536 (W) + WPB*8*132*4 (agg, padded stride 132) = 133120 B -> 1 block/CU.
__global__ __launch_bounds__(1024, 4) void gcn_layer_fused(
    const float* __restrict__ hin, const int* __restrict__ off,
    const int2* __restrict__ csr, const float* __restrict__ dinv,
    const float* __restrict__ Wg, const float* __restrict__ bias,
    float* __restrict__ hout, int final_layout) {
    extern __shared__ float smem[];
    float* Wl = smem;                    // [128][128]
    float* aggAll = smem + 128 * 128;    // [WPB][8][132]

    const int tid = threadIdx.x;
    {
        const float4* src4 = (const float4*)Wg;
        float4* dst4 = (float4*)Wl;
#pragma unroll
        for (int i = 0; i < 4; ++i) dst4[tid + i * 1024] = src4[tid + i * 1024];
    }
    __syncthreads();   // only block-wide sync; waves independent after this

    const int w = tid >> 6, l = tid & 63;
    const int n = blockIdx.x * WPB + w;
    const float d = dinv[n];
    const float d2 = d * d;
    const float4* hb = (const float4*)hin;
    const size_t nb = (size_t)n * 256;

    float4 a0 = hb[nb + l];
    float4 a1 = hb[nb + 64 + l];
    float4 a2 = hb[nb + 128 + l];
    float4 a3 = hb[nb + 192 + l];
    a0.x *= d2; a0.y *= d2; a0.z *= d2; a0.w *= d2;
    a1.x *= d2; a1.y *= d2; a1.z *= d2; a1.w *= d2;
    a2.x *= d2; a2.y *= d2; a2.z *= d2; a2.w *= d2;
    a3.x *= d2; a3.y *= d2; a3.z *= d2; a3.w *= d2;

    const int s = off[n], e = off[n + 1];
    for (int p = s; p < e; p += 4) {
        int si[4]; float wv[4];
#pragma unroll
        for (int u = 0; u < 4; ++u) {
            int q = (p + u < e) ? (p + u) : (e - 1);
            int2 sw = csr[q];
            si[u] = sw.x;
            wv[u] = (p + u < e) ? __int_as_float(sw.y) : 0.0f;
        }
        float4 vv[4][4];
#pragma unroll
        for (int u = 0; u < 4; ++u) {
            size_t sb = (size_t)si[u] * 256;
#pragma unroll
            for (int c = 0; c < 4; ++c) vv[u][c] = hb[sb + 64 * c + l];
        }
#pragma unroll
        for (int u = 0; u < 4; ++u) {
            float ww = wv[u];
            a0.x += ww * vv[u][0].x; a0.y += ww * vv[u][0].y;
            a0.z += ww * vv[u][0].z; a0.w += ww * vv[u][0].w;
            a1.x += ww * vv[u][1].x; a1.y += ww * vv[u][1].y;
            a1.z += ww * vv[u][1].z; a1.w += ww * vv[u][1].w;
            a2.x += ww * vv[u][2].x; a2.y += ww * vv[u][2].y;
            a2.z += ww * vv[u][2].z; a2.w += ww * vv[u][2].w;
            a3.x += ww * vv[u][3].x; a3.y += ww * vv[u][3].y;
            a3.z += ww * vv[u][3].z; a3.w += ww * vv[u][3].w;
        }
    }

    // stash row into private LDS tile: chunk c=64*i+l -> row b=2i+(l>>5), col (l&31)*4
    float* aw = aggAll + w * (8 * 132);
    const int b0 = l >> 5;
    const int c0 = (l & 31) * 4;
    *(float4*)&aw[(b0 + 0) * 132 + c0] = a0;
    *(float4*)&aw[(b0 + 2) * 132 + c0] = a1;
    *(float4*)&aw[(b0 + 4) * 132 + c0] = a2;
    *(float4*)&aw[(b0 + 6) * 132 + c0] = a3;
    asm volatile("s_waitcnt lgkmcnt(0)" ::: "memory");  // wave-local: writes visible

    // GEMM: lane -> rows {2rg, 2rg+1}, cols cg*8..cg*8+7
    const int rg = l >> 4;
    const int cg = l & 15;
    const float* a0p = aw + (2 * rg) * 132;
    const float* a1p = a0p + 132;
    float o0[8] = {}, o1[8] = {};
#pragma unroll 4
    for (int k = 0; k < 128; ++k) {
        float x0 = a0p[k], x1 = a1p[k];
        float4 w0 = *(const float4*)&Wl[k * 128 + cg * 8];
        float4 w1 = *(const float4*)&Wl[k * 128 + cg * 8 + 4];
        o0[0] += x0 * w0.x; o0[1] += x0 * w0.y; o0[2] += x0 * w0.z; o0[3] += x0 * w0.w;
        o0[4] += x0 * w1.x; o0[5] += x0 * w1.y; o0[6] += x0 * w1.z; o0[7] += x0 * w1.w;
        o1[0] += x1 * w0.x; o1[1] += x1 * w0.y; o1[2] += x1 * w0.z; o1[3] += x1 * w0.w;
        o1[4] += x1 * w1.x; o1[5] += x1 * w1.y; o1[6] += x1 * w1.z; o1[7] += x1 * w1.w;
    }
    float4 bi0 = *(const float4*)&bias[cg * 8];
    float4 bi1 = *(const float4*)&bias[cg * 8 + 4];
    float4 r00, r01, r10, r11;
    r00.x = fmaxf(o0[0] + bi0.x, 0.0f); r00.y = fmaxf(o0[1] + bi0.y, 0.0f);
    r00.z = fmaxf(o0[2] + bi0.z, 0.0f); r00.w = fmaxf(o0[3] + bi0.w, 0.0f);
    r01.x = fmaxf(o0[4] + bi1.x, 0.0f); r01.y = fmaxf(o0[5] + bi1.y, 0.0f);
    r01.z = fmaxf(o0[6] + bi1.z, 0.0f); r01.w = fmaxf(o0[7] + bi1.w, 0.0f);
    r10.x = fmaxf(o1[0] + bi0.x, 0.0f); r10.y = fmaxf(o1[1] + bi0.y, 0.0f);
    r10.z = fmaxf(o1[2] + bi0.z, 0.0f); r10.w = fmaxf(o1[3] + bi0.w, 0.0f);
    r11.x = fmaxf(o1[4] + bi1.x, 0.0f); r11.y = fmaxf(o1[5] + bi1.y, 0.0f);
    r11.z = fmaxf(o1[6] + bi1.z, 0.0f); r11.w = fmaxf(o1[7] + bi1.w, 0.0f);

    const int b = 2 * rg;
    size_t r0 = final_layout ? ((size_t)b * N_NODES + n) : ((size_t)n * 8 + b);
    size_t r1 = final_layout ? ((size_t)(b + 1) * N_NODES + n) : ((size_t)n * 8 + b + 1);
    *(float4*)&hout[r0 * HID + cg * 8] = r00;
    *(float4*)&hout[r0 * HID + cg * 8 + 4] = r01;
    *(float4*)&hout[r1 * HID + cg * 8] = r10;
    *(float4*)&hout[r1 * HID + cg * 8 + 4] = r11;
}

extern "C" void kernel_launch(void* const* d_in, const int* in_sizes, int n_in,
                              void* d_out, int out_size, void* d_ws, size_t ws_size,
                              hipStream_t stream) {
    const float* x      = (const float*)d_in[0];
    const float* fixedf = (const float*)d_in[1];
    const float* W_in   = (const float*)d_in[2];
    const float* b_in   = (const float*)d_in[3];
    const float* Wg     = (const float*)d_in[4];
    const float* bg     = (const float*)d_in[5];
    const int*   ei     = (const int*)d_in[6];

    const int* rowi = ei;
    const int* coli = ei + N_EDGES;

    char* ws = (char*)d_ws;
    int*   deg     = (int*)(ws + O_DEG);
    int*   cursor  = (int*)(ws + O_CUR);
    int*   off     = (int*)(ws + O_OFF);
    float* dinv    = (float*)(ws + O_DINV);
    int2*  csr     = (int2*)(ws + O_CSR);
    float* hA      = (float*)(ws + O_HBUF);
    float* hB      = (float*)d_out;

    hipMemsetAsync(deg, 0, N_NODES * sizeof(int), stream);
    hipMemsetAsync(cursor, 0, N_NODES * sizeof(int), stream);

    count_deg<<<(N_EDGES + 255) / 256, 256, 0, stream>>>(coli, deg);
    compute_dinv<<<(N_NODES + 255) / 256, 256, 0, stream>>>(deg, dinv);
    scan_offsets<<<1, 1024, 0, stream>>>(deg, off);
    fill_csr<<<(N_EDGES + 255) / 256, 256, 0, stream>>>(rowi, coli, dinv, off, cursor, csr);

    input_proj<<<N_NODES, 256, 0, stream>>>(x, fixedf, W_in, b_in, hA);

    constexpr size_t LDS_BYTES = (size_t)(128 * 128 + WPB * 8 * 132) * 4;  // 133120
    hipFuncSetAttribute((const void*)gcn_layer_fused,
                        hipFuncAttributeMaxDynamicSharedMemorySize, (int)LDS_BYTES);

    const int FB = N_NODES / WPB;   // 1250 blocks

    // L0: hA -> hB(d_out); L1: hB -> hA; L2: hA -> d_out (final [b][n][h] layout)
    gcn_layer_fused<<<FB, 1024, LDS_BYTES, stream>>>(hA, off, csr, dinv,
        Wg + 0 * HID * HID, bg + 0 * HID, hB, 0);
    gcn_layer_fused<<<FB, 1024, LDS_BYTES, stream>>>(hB, off, csr, dinv,
        Wg + 1 * HID * HID, bg + 1 * HID, hA, 0);
    gcn_layer_fused<<<FB, 1024, LDS_BYTES, stream>>>(hA, off, csr, dinv,
        Wg + 2 * HID * HID, bg + 2 * HID, (float*)d_out, 1);
}